// Round 14
// baseline (332.695 us; speedup 1.0000x reference)
//
#include <hip/hip_runtime.h>
#include <hip/hip_bf16.h>
#include <hip/hip_fp16.h>
#include <cstdint>

typedef __attribute__((ext_vector_type(4))) float f32x4;
typedef __attribute__((ext_vector_type(8))) short s16x8;

#define DEVI static __device__ __forceinline__

constexpr int Bc = 8, Tc = 2048, Sc = 8, Dc = 256;
constexpr int Mc = Bc * Tc * Sc;  // 131072 rows

DEVI unsigned short f2bf(float x) {
  return __bfloat16_as_ushort(__float2bfloat16(x));
}

DEVI f32x4 mfma16(s16x8 a, s16x8 b, f32x4 c) {
  return __builtin_amdgcn_mfma_f32_16x16x32_bf16(a, b, c, 0, 0, 0);
}

// async global->LDS, 16B per lane (dest must be wave-uniform base + lane*16)
DEVI void gld16(const void* g, void* l) {
  __builtin_amdgcn_global_load_lds(
      (const __attribute__((address_space(1))) unsigned int*)g,
      (__attribute__((address_space(3))) unsigned int*)l, 16, 0, 0);
}

// ---------------- x f32 -> bf16 ----------------
__global__ void cvt_x_k(const float* __restrict__ in, unsigned short* __restrict__ out, int n) {
  int i = (blockIdx.x * blockDim.x + threadIdx.x) * 8;
  int stride = gridDim.x * blockDim.x * 8;
  for (; i < n; i += stride) {
    f32x4 a = *(const f32x4*)(in + i);
    f32x4 b = *(const f32x4*)(in + i + 4);
    s16x8 o;
    o[0] = (short)f2bf(a[0]); o[1] = (short)f2bf(a[1]);
    o[2] = (short)f2bf(a[2]); o[3] = (short)f2bf(a[3]);
    o[4] = (short)f2bf(b[0]); o[5] = (short)f2bf(b[1]);
    o[6] = (short)f2bf(b[2]); o[7] = (short)f2bf(b[3]);
    *(s16x8*)(out + i) = o;
  }
}

// ---------------- weight transpose+convert ----------------
__global__ void cvtW_k(const float* __restrict__ Win, const float* __restrict__ Wout,
                       unsigned short* __restrict__ wtin, unsigned short* __restrict__ wtout) {
  int tid = blockIdx.x * blockDim.x + threadIdx.x;
  if (tid < 512 * 256) {
    int c = tid >> 8, r = tid & 255;
    wtin[tid] = f2bf(Win[r * 512 + c]);
  } else {
    int t = tid - 512 * 256;
    int c = t >> 8, r = t & 255;
    wtout[t] = f2bf(Wout[r * 256 + c]);
  }
}

// ---------------- fused GEMM1 + activation + scan, quarter-K ring ----------------
// Grid 1024 = (b,s,dq16); 256 threads = 4 waves = 4 rg (16t x 16d each, full K per
// wave -- no cross-wave K reduction). As = ring[2] x 8KB (64 rows x 64 K); 4
// phases/chunk, 1 barrier each; stage(p+2) after the barrier freeing its buffer.
// LDS 18 KB -> 8 blocks/CU (32 waves, full occupancy). Scan tail at sub3 as r13.
__global__ __launch_bounds__(256, 8) void g1scan_k(
    const unsigned short* __restrict__ xb,   // [M][256] bf16
    const unsigned short* __restrict__ wt,   // [512][256] bf16 = W_in^T
    const float* __restrict__ bias,          // [512]
    unsigned short* __restrict__ yb)         // [M][256] bf16
{
  __shared__ unsigned short As[2][2 * 64 * 32];    // ring: 2 x 8KB, [buf][kfl][row][32]
  __shared__ float segA[2][4][16], segB[2][4][16]; // 1 KB

  int bid = blockIdx.x;
  int lb = (bid & 7) * 128 + (bid >> 3);           // XCD x owns batch b = x
  int b = lb >> 7, s = (lb >> 4) & 7, dq = lb & 15;
  int tid = threadIdx.x;
  int lane = tid & 63, rg = tid >> 6;              // 4 waves = 4 t-row groups
  int lo = lane & 15, hi = lane >> 4;
  int cl = lo;                                     // d-local col in [0,16)
  int kg = hi * 8;

  const short* xs = (const short*)xb;
  const short* wsrc = (const short*)wt;
  size_t rowbase = (size_t)b * 16384 + s;          // global row = rowbase + t*8

  // W fragments (compiler re-materializes from L2 as needed)
  s16x8 bGr[8], bCr[8];
  #pragma unroll
  for (int kf = 0; kf < 8; ++kf) {
    bGr[kf] = *(const s16x8*)(wsrc + (size_t)(dq * 16 + cl) * 256 + kf * 32 + kg);
    bCr[kf] = *(const s16x8*)(wsrc + (size_t)(256 + dq * 16 + cl) * 256 + kf * 32 + kg);
  }
  float bg = bias[dq * 16 + cl];
  float bc = bias[256 + dq * 16 + cl];

  // staging: phase buffer = 512 x 16B chunks; j = q*256+tid:
  // kfl = j>>8, row = (j&255)>>2, cc = j&3
  const short* pA[2];
  int ldso[2];
  #pragma unroll
  for (int q = 0; q < 2; ++q) {
    int j = q * 256 + tid;
    int kfl = j >> 8, rem = j & 255, r = rem >> 2, cc = j & 3;
    pA[q] = xs + (rowbase + (size_t)r * 8) * 256 + kfl * 32 + cc * 8;
    ldso[q] = j * 8;
  }
  const size_t ASTRIDE = (size_t)64 * 8 * 256;     // shorts per 64-t chunk

  // prologue: stage phases 0 (buf0) and 1 (buf1); pA -> phase 2
  #pragma unroll
  for (int q = 0; q < 2; ++q) gld16(pA[q], (unsigned short*)As[0] + ldso[q]);
  #pragma unroll
  for (int q = 0; q < 2; ++q) gld16(pA[q] + 64, (unsigned short*)As[1] + ldso[q]);
  #pragma unroll
  for (int q = 0; q < 2; ++q) pA[q] += 128;

  float stt = 0.f;   // scan carry (identical across threads of same d)

  __syncthreads();

  for (int ch = 0; ch < 32; ++ch) {
    f32x4 accG = {}, accC = {};
    float av[4], bv[4], eA, eB;

    #pragma unroll
    for (int sub = 0; sub < 4; ++sub) {
      int buf = sub & 1;
      const unsigned short* Ab = (const unsigned short*)As[buf];
      // ---- GEMM: 2 kf panels of this K-quarter ----
      #pragma unroll
      for (int kfl = 0; kfl < 2; ++kfl) {
        int kf = sub * 2 + kfl;
        s16x8 aF = *(const s16x8*)(Ab + kfl * 2048 + (rg * 16 + lo) * 32 + kg);
        accG = mfma16(aF, bGr[kf], accG);
        accC = mfma16(aF, bCr[kf], accC);
      }

      if (sub == 3) {
        // ---- activation + compose + in-wave prefix + publish (before barrier) ----
        #pragma unroll
        for (int r = 0; r < 4; ++r) {
          float g = accG[r] + bg;
          float c = accC[r] + bc;
          float alpha = 1.f / (1.f + __expf(-g));
          float e2 = __expf(2.f * c);
          float th = 1.f - 2.f / (e2 + 1.f);   // tanh(c)
          av[r] = 1.f - alpha;
          bv[r] = alpha * th;
        }
        float iA = av[0], iB = bv[0];
        #pragma unroll
        for (int r = 1; r < 4; ++r) { iA = iA * av[r]; iB = fmaf(av[r], iB, bv[r]); }
        {
          float tA = __shfl_up(iA, 16), tB = __shfl_up(iB, 16);
          float nA = tA * iA, nB = fmaf(iA, tB, iB);
          if (hi >= 1) { iA = nA; iB = nB; }
          tA = __shfl_up(iA, 32); tB = __shfl_up(iB, 32);
          nA = tA * iA; nB = fmaf(iA, tB, iB);
          if (hi >= 2) { iA = nA; iB = nB; }
        }
        eA = __shfl_up(iA, 16); eB = __shfl_up(iB, 16);
        if (hi == 0) { eA = 1.f; eB = 0.f; }
        if (hi == 3) { segA[ch & 1][rg][cl] = iA; segB[ch & 1][rg][cl] = iB; }
      }

      __syncthreads();   // frees As[buf]; drains stage issued 2 phases ago; segs visible at sub3

      // ---- stage phase p+2 into the just-freed buffer ----
      if (!(ch == 31 && sub >= 2)) {
        #pragma unroll
        for (int q = 0; q < 2; ++q) gld16(pA[q], (unsigned short*)As[buf] + ldso[q]);
        #pragma unroll
        for (int q = 0; q < 2; ++q) pA[q] += (sub == 1) ? (ASTRIDE - 192) : 64;
      }
    }

    // ---- cross-wave walk over 4 rg segments + apply + store ----
    int cur = ch & 1;
    float run = stt, s_w = stt;
    #pragma unroll
    for (int r2 = 0; r2 < 4; ++r2) {
      if (r2 == rg) s_w = run;
      run = fmaf(segA[cur][r2][cl], run, segB[cur][r2][cl]);
    }
    stt = run;

    float sv = fmaf(eA, s_w, eB);
    size_t ybase = (rowbase + (size_t)(ch * 64 + rg * 16 + hi * 4) * 8) * 256 + dq * 16 + cl;
    #pragma unroll
    for (int u = 0; u < 4; ++u) {
      sv = fmaf(av[u], sv, bv[u]);
      yb[ybase + (size_t)u * 8 * 256] = f2bf(sv);
    }
  }
}

// ---------------- GEMM2: out = y@W_out + b_out ----------------
// BK=32, LDS 32KB -> 4 blocks/CU. grid 2048 = 1024 mtiles x 2 ctiles.
__global__ __launch_bounds__(256, 4) void gemm2_k(
    const unsigned short* __restrict__ yb,   // [M][256] bf16
    const unsigned short* __restrict__ wt,   // [256][256] bf16 = W_out^T
    const float* __restrict__ bias,          // [256]
    float* __restrict__ out)
{
  __shared__ unsigned short As[2][128 * 32];
  __shared__ unsigned short Bs[2][128 * 32];

  int bid = blockIdx.x;
  int swz = (bid & 7) * 256 + (bid >> 3);
  int mtile = swz >> 1, ctile = swz & 1;
  int tid = threadIdx.x;
  int lane = tid & 63, wave = tid >> 6;
  int wr = wave >> 1, wc = wave & 1;

  const short* ys = (const short*)yb;
  const short* wsrc = (const short*)wt;

  int srow = tid >> 2, sch = (tid & 3) * 8;
  size_t gArow = (size_t)(mtile * 128 + srow) * 256;
  size_t gBrow = (size_t)(ctile * 128 + srow) * 256;

  auto STAGE = [&](int buf, int k0) {
    gld16(ys + gArow + k0 + sch,                    &As[buf][(size_t)tid * 8]);
    gld16(ys + gArow + (size_t)64 * 256 + k0 + sch, &As[buf][2048 + (size_t)tid * 8]);
    gld16(wsrc + gBrow + k0 + sch,                    &Bs[buf][(size_t)tid * 8]);
    gld16(wsrc + gBrow + (size_t)64 * 256 + k0 + sch, &Bs[buf][2048 + (size_t)tid * 8]);
  };

  f32x4 acc[4][4] = {};

  STAGE(0, 0);
  __syncthreads();
  #pragma unroll
  for (int kk = 0; kk < 8; ++kk) {
    int cur = kk & 1;
    if (kk < 7) STAGE(cur ^ 1, (kk + 1) * 32);
    int kg = (lane >> 4) * 8;
    s16x8 aF[4], bF[4];
    #pragma unroll
    for (int mf = 0; mf < 4; ++mf)
      aF[mf] = *(const s16x8*)&As[cur][(wr * 64 + mf * 16 + (lane & 15)) * 32 + kg];
    #pragma unroll
    for (int nf = 0; nf < 4; ++nf)
      bF[nf] = *(const s16x8*)&Bs[cur][(wc * 64 + nf * 16 + (lane & 15)) * 32 + kg];
    #pragma unroll
    for (int mf = 0; mf < 4; ++mf)
      #pragma unroll
      for (int nf = 0; nf < 4; ++nf)
        acc[mf][nf] = mfma16(aF[mf], bF[nf], acc[mf][nf]);
    __syncthreads();
  }

  int orow0 = mtile * 128 + wr * 64 + (lane >> 4) * 4;
  #pragma unroll
  for (int nf = 0; nf < 4; ++nf) {
    int col = ctile * 128 + wc * 64 + nf * 16 + (lane & 15);
    float bo = bias[col];
    #pragma unroll
    for (int mf = 0; mf < 4; ++mf) {
      #pragma unroll
      for (int r = 0; r < 4; ++r) {
        int row = orow0 + mf * 16 + r;
        out[(size_t)row * 256 + col] = acc[mf][nf][r] + bo;
      }
    }
  }
}

// ---------------- host ----------------
extern "C" void kernel_launch(void* const* d_in, const int* in_sizes, int n_in,
                              void* d_out, int out_size, void* d_ws, size_t ws_size,
                              hipStream_t stream)
{
  const float* x    = (const float*)d_in[0];
  const float* Win  = (const float*)d_in[1];
  const float* bin  = (const float*)d_in[2];
  const float* Wout = (const float*)d_in[3];
  const float* bout = (const float*)d_in[4];
  float* out = (float*)d_out;
  char* ws = (char*)d_ws;

  // ws layout: Wt_in (256 KiB) | Wt_out (128 KiB) | yb (64 MiB) | xb (64 MiB)
  unsigned short* wtin  = (unsigned short*)(ws);
  unsigned short* wtout = (unsigned short*)(ws + 262144);
  unsigned short* yb    = (unsigned short*)(ws + 393216);
  unsigned short* xb    = (unsigned short*)(ws + 393216 + (size_t)Mc * 256 * 2);

  cvt_x_k<<<1024, 256, 0, stream>>>(x, xb, Mc * 256);
  cvtW_k<<<768, 256, 0, stream>>>(Win, Wout, wtin, wtout);
  g1scan_k<<<1024, 256, 0, stream>>>(xb, wtin, bin, yb);
  gemm2_k<<<2048, 256, 0, stream>>>(yb, wtout, bout, out);
}

// Round 15
// 155.338 us; speedup vs baseline: 2.1417x; 2.1417x over previous
//
#include <hip/hip_runtime.h>
#include <hip/hip_bf16.h>
#include <hip/hip_fp16.h>
#include <cstdint>

typedef __attribute__((ext_vector_type(4))) float f32x4;
typedef __attribute__((ext_vector_type(8))) short s16x8;

#define DEVI static __device__ __forceinline__

constexpr int Bc = 8, Tc = 2048, Sc = 8, Dc = 256;
constexpr int Mc = Bc * Tc * Sc;  // 131072 rows

// plain-cast f32->bf16 (RNE): compiler packs pairs into v_cvt_pk_bf16_f32
DEVI unsigned short f2bf(float x) {
  return __bfloat16_as_ushort(__float2bfloat16(x));
}

DEVI f32x4 mfma16(s16x8 a, s16x8 b, f32x4 c) {
  return __builtin_amdgcn_mfma_f32_16x16x32_bf16(a, b, c, 0, 0, 0);
}

// async global->LDS, 16B per lane (dest must be wave-uniform base + lane*16)
DEVI void gld16(const void* g, void* l) {
  __builtin_amdgcn_global_load_lds(
      (const __attribute__((address_space(1))) unsigned int*)g,
      (__attribute__((address_space(3))) unsigned int*)l, 16, 0, 0);
}

// ---------------- x f32 -> bf16 ----------------
__global__ void cvt_x_k(const float* __restrict__ in, unsigned short* __restrict__ out, int n) {
  int i = (blockIdx.x * blockDim.x + threadIdx.x) * 8;
  int stride = gridDim.x * blockDim.x * 8;
  for (; i < n; i += stride) {
    f32x4 a = *(const f32x4*)(in + i);
    f32x4 b = *(const f32x4*)(in + i + 4);
    s16x8 o;
    o[0] = (short)f2bf(a[0]); o[1] = (short)f2bf(a[1]);
    o[2] = (short)f2bf(a[2]); o[3] = (short)f2bf(a[3]);
    o[4] = (short)f2bf(b[0]); o[5] = (short)f2bf(b[1]);
    o[6] = (short)f2bf(b[2]); o[7] = (short)f2bf(b[3]);
    *(s16x8*)(out + i) = o;
  }
}

// ---------------- weight transpose+convert (both W in one kernel) ----------------
__global__ void cvtW_k(const float* __restrict__ Win, const float* __restrict__ Wout,
                       unsigned short* __restrict__ wtin, unsigned short* __restrict__ wtout) {
  int tid = blockIdx.x * blockDim.x + threadIdx.x;
  if (tid < 512 * 256) {
    int c = tid >> 8, r = tid & 255;
    wtin[tid] = f2bf(Win[r * 512 + c]);
  } else {
    int t = tid - 512 * 256;
    int c = t >> 8, r = t & 255;
    wtout[t] = f2bf(Wout[r * 256 + c]);
  }
}

// ---------------- fused GEMM1 + activation + scan (1 barrier/chunk) ----------------
// r13 structure (known-good): grid 512 = (b,s,dq8), 512 threads = 4 rg x 2 cg.
// Scan composition per-thread + __shfl_up in-wave prefix; 1 KB dbuf segs; ONE
// barrier/chunk. THIS ROUND: activation divisions replaced with v_rcp_f32
// (each full-precision f32 div = ~10 VALU; two per element sat on the
// barrier-coupled critical path; rcp ~1ulp << bf16 threshold).
__global__ __launch_bounds__(512, 2) void g1scan_k(
    const unsigned short* __restrict__ xb,   // [M][256] bf16
    const unsigned short* __restrict__ wt,   // [512][256] bf16 = W_in^T
    const float* __restrict__ bias,          // [512]
    unsigned short* __restrict__ yb)         // [M][256] bf16
{
  __shared__ unsigned short As[2][8 * 64 * 32];   // 2 x 32 KB; [buf][kf][row64][32]
  __shared__ float segA[2][4][32], segB[2][4][32]; // 2 KB wave-segment pairs

  int bid = blockIdx.x;
  int lb = (bid & 7) * 64 + (bid >> 3);           // XCD x owns batch b = x
  int b = lb >> 6, s = (lb >> 3) & 7, dq = lb & 7;
  int tid = threadIdx.x;
  int lane = tid & 63, wave = tid >> 6;
  int rg = wave >> 1, cg = wave & 1;              // 4 t-row groups x 2 col groups
  int lo = lane & 15, hi = lane >> 4;

  const short* xs = (const short*)xb;
  const short* wsrc = (const short*)wt;
  size_t rowbase = (size_t)b * 16384 + s;         // global row = rowbase + t*8

  int cl = cg * 16 + lo;                          // d-local col in [0,32)
  int kg = hi * 8;

  // ---- W fragments: global -> registers (one-time, L2-resident weights) ----
  s16x8 bGr[8], bCr[8];
  #pragma unroll
  for (int kf = 0; kf < 8; ++kf) {
    bGr[kf] = *(const s16x8*)(wsrc + (size_t)(dq * 32 + cl) * 256 + kf * 32 + kg);
    bCr[kf] = *(const s16x8*)(wsrc + (size_t)(256 + dq * 32 + cl) * 256 + kf * 32 + kg);
  }
  float bg = bias[dq * 32 + cl];
  float bc = bias[256 + dq * 32 + cl];

  // ---- incremental A-staging pointers: 2048 16B chunks/tile, 4 per thread ----
  const short* pA[4];
  int ldso[4];
  #pragma unroll
  for (int q = 0; q < 4; ++q) {
    int j = q * 512 + tid;
    int kf = j >> 8, rem = j & 255, r = rem >> 2, cc = j & 3;
    pA[q] = xs + (rowbase + (size_t)r * 8) * 256 + kf * 32 + cc * 8;
    ldso[q] = j * 8;
  }
  const size_t ASTRIDE = (size_t)64 * 8 * 256;    // shorts per 64-t chunk

  // prologue: stage chunks 0 and 1
  #pragma unroll
  for (int q = 0; q < 4; ++q) gld16(pA[q], (unsigned short*)As[0] + ldso[q]);
  #pragma unroll
  for (int q = 0; q < 4; ++q) gld16(pA[q] + ASTRIDE, (unsigned short*)As[1] + ldso[q]);
  #pragma unroll
  for (int q = 0; q < 4; ++q) pA[q] += 2 * ASTRIDE;

  float stt = 0.f;   // block scan carry (identical across all threads of same d)

  __syncthreads();   // drains prologue stages

  for (int ch = 0; ch < 32; ++ch) {
    int cur = ch & 1;
    const unsigned short* Ab = (const unsigned short*)As[cur];

    // ---- GEMM: this thread ends with t = ch*64 + rg*16 + hi*4 + [0,4), d = cl ----
    f32x4 accG = {}, accC = {};
    #pragma unroll
    for (int kf = 0; kf < 8; ++kf) {
      s16x8 aF = *(const s16x8*)(Ab + kf * 2048 + (rg * 16 + lo) * 32 + kg);
      accG = mfma16(aF, bGr[kf], accG);
      accC = mfma16(aF, bCr[kf], accC);
    }

    // ---- activation in-register: v_rcp instead of full-precision div ----
    float av[4], bv[4];
    #pragma unroll
    for (int r = 0; r < 4; ++r) {
      float g = accG[r] + bg;
      float c = accC[r] + bc;
      float eg = __expf(-g);                              // v_mul + v_exp
      float alpha = __builtin_amdgcn_rcpf(1.f + eg);      // ~1ulp, saturates ok
      float e2 = __expf(2.f * c);
      float th = 1.f - 2.f * __builtin_amdgcn_rcpf(e2 + 1.f);  // tanh(c)
      av[r] = 1.f - alpha;
      bv[r] = alpha * th;
    }

    // ---- per-thread compose over its 4 t-steps ----
    float iA = av[0], iB = bv[0];
    #pragma unroll
    for (int r = 1; r < 4; ++r) { iA = iA * av[r]; iB = fmaf(av[r], iB, bv[r]); }

    // ---- in-wave inclusive prefix over hi (4 groups) ----
    {
      float tA = __shfl_up(iA, 16), tB = __shfl_up(iB, 16);
      float nA = tA * iA, nB = fmaf(iA, tB, iB);
      if (hi >= 1) { iA = nA; iB = nB; }
      tA = __shfl_up(iA, 32); tB = __shfl_up(iB, 32);
      nA = tA * iA; nB = fmaf(iA, tB, iB);
      if (hi >= 2) { iA = nA; iB = nB; }
    }
    // exclusive-within-wave for this thread
    float eA = __shfl_up(iA, 16), eB = __shfl_up(iB, 16);
    if (hi == 0) { eA = 1.f; eB = 0.f; }
    // publish wave segment (inclusive at hi==3)
    if (hi == 3) { segA[cur][rg][cl] = iA; segB[cur][rg][cl] = iB; }

    __syncthreads();   // THE barrier: As dbuf + segs + drains stage(ch+1)

    // ---- issue chunk ch+2 staging into the just-freed buffer ----
    if (ch + 2 < 32) {
      #pragma unroll
      for (int q = 0; q < 4; ++q) gld16(pA[q], (unsigned short*)As[cur] + ldso[q]);
      #pragma unroll
      for (int q = 0; q < 4; ++q) pA[q] += ASTRIDE;
    }

    // ---- cross-wave walk over 4 rg segments (redundant, identical per d) ----
    float run = stt, s_w = stt;
    #pragma unroll
    for (int r2 = 0; r2 < 4; ++r2) {
      if (r2 == rg) s_w = run;
      run = fmaf(segA[cur][r2][cl], run, segB[cur][r2][cl]);
    }
    stt = run;                            // carry into next chunk

    // ---- apply: start = excl-wave o carry, then own 4 steps + store ----
    float sv = fmaf(eA, s_w, eB);
    size_t ybase = (rowbase + (size_t)(ch * 64 + rg * 16 + hi * 4) * 8) * 256 + dq * 32 + cl;
    #pragma unroll
    for (int u = 0; u < 4; ++u) {
      sv = fmaf(av[u], sv, bv[u]);
      yb[ybase + (size_t)u * 8 * 256] = f2bf(sv);
    }
  }
}

// ---------------- GEMM2: out = y@W_out + b_out ----------------
// BK=64 as two [128][32] sub-panels. grid 2048 = 1024 mtiles x 2 ctiles.
__global__ __launch_bounds__(256, 2) void gemm2_k(
    const unsigned short* __restrict__ yb,   // [M][256] bf16
    const unsigned short* __restrict__ wt,   // [256][256] bf16 = W_out^T
    const float* __restrict__ bias,          // [256]
    float* __restrict__ out)
{
  __shared__ unsigned short As[2][2][128 * 32];
  __shared__ unsigned short Bs[2][2][128 * 32];

  int bid = blockIdx.x;
  int swz = (bid & 7) * 256 + (bid >> 3);
  int mtile = swz >> 1, ctile = swz & 1;
  int tid = threadIdx.x;
  int lane = tid & 63, wave = tid >> 6;
  int wr = wave >> 1, wc = wave & 1;

  const short* ys = (const short*)yb;
  const short* wsrc = (const short*)wt;

  auto STAGE = [&](int buf, int k0) {
    unsigned short* Ad = &As[buf][0][0];
    unsigned short* Bd = &Bs[buf][0][0];
    #pragma unroll
    for (int q = 0; q < 4; ++q) {
      int j = q * 256 + tid;
      int p = j >> 9, r = (j >> 2) & 127, cc = j & 3;
      int koff = k0 + p * 32 + cc * 8;
      gld16(ys + (size_t)(mtile * 128 + r) * 256 + koff, Ad + (size_t)j * 8);
      gld16(wsrc + (size_t)(ctile * 128 + r) * 256 + koff, Bd + (size_t)j * 8);
    }
  };

  f32x4 acc[4][4] = {};

  STAGE(0, 0);
  __syncthreads();
  #pragma unroll
  for (int kk = 0; kk < 4; ++kk) {
    int cur = kk & 1;
    if (kk < 3) STAGE(cur ^ 1, (kk + 1) * 64);
    int kg = (lane >> 4) * 8;
    #pragma unroll
    for (int ks = 0; ks < 2; ++ks) {
      s16x8 aF[4], bF[4];
      #pragma unroll
      for (int mf = 0; mf < 4; ++mf)
        aF[mf] = *(const s16x8*)&As[cur][ks][(wr * 64 + mf * 16 + (lane & 15)) * 32 + kg];
      #pragma unroll
      for (int nf = 0; nf < 4; ++nf)
        bF[nf] = *(const s16x8*)&Bs[cur][ks][(wc * 64 + nf * 16 + (lane & 15)) * 32 + kg];
      #pragma unroll
      for (int mf = 0; mf < 4; ++mf)
        #pragma unroll
        for (int nf = 0; nf < 4; ++nf)
          acc[mf][nf] = mfma16(aF[mf], bF[nf], acc[mf][nf]);
    }
    if (kk < 3) __syncthreads();
  }

  int orow0 = mtile * 128 + wr * 64 + (lane >> 4) * 4;
  #pragma unroll
  for (int nf = 0; nf < 4; ++nf) {
    int col = ctile * 128 + wc * 64 + nf * 16 + (lane & 15);
    float bo = bias[col];
    #pragma unroll
    for (int mf = 0; mf < 4; ++mf) {
      #pragma unroll
      for (int r = 0; r < 4; ++r) {
        int row = orow0 + mf * 16 + r;
        out[(size_t)row * 256 + col] = acc[mf][nf][r] + bo;
      }
    }
  }
}

// ---------------- host ----------------
extern "C" void kernel_launch(void* const* d_in, const int* in_sizes, int n_in,
                              void* d_out, int out_size, void* d_ws, size_t ws_size,
                              hipStream_t stream)
{
  const float* x    = (const float*)d_in[0];
  const float* Win  = (const float*)d_in[1];
  const float* bin  = (const float*)d_in[2];
  const float* Wout = (const float*)d_in[3];
  const float* bout = (const float*)d_in[4];
  float* out = (float*)d_out;
  char* ws = (char*)d_ws;

  // ws layout: Wt_in (256 KiB) | Wt_out (128 KiB) | yb (64 MiB) | xb (64 MiB)
  unsigned short* wtin  = (unsigned short*)(ws);
  unsigned short* wtout = (unsigned short*)(ws + 262144);
  unsigned short* yb    = (unsigned short*)(ws + 393216);
  unsigned short* xb    = (unsigned short*)(ws + 393216 + (size_t)Mc * 256 * 2);

  cvt_x_k<<<1024, 256, 0, stream>>>(x, xb, Mc * 256);
  cvtW_k<<<768, 256, 0, stream>>>(Win, Wout, wtin, wtout);
  g1scan_k<<<512, 512, 0, stream>>>(xb, wtin, bin, yb);
  gemm2_k<<<2048, 256, 0, stream>>>(yb, wtout, bout, out);
}